// Round 14
// baseline (65.450 us; speedup 1.0000x reference)
//
#include <hip/hip_runtime.h>

// MoV3D: 3D local attention, window +-2 (125 offsets), B=2 C=32 H=W=D=48, 4 heads x 8 ch.
// ROUND 14: VZ=2 re-attempt (r9 failed on occupancy + OCML exp2; both now fixed).
// Tile 8x8x8 cube, 2 z-voxels/thread (256 thr: tzi=tid&3, ty=(tid>>2)&7, tx=tid>>5).
// Halo 12x12x12, LDS line (16B) = 8 head channels (fp16 pairs) at one halo point:
//   line = lx*145 + lz*12 + ly   (lx stride 145 = 1 mod 8: stride-8 lane phases vary
//   ty by 2 (ly coeff 1 -> {0,2,4,6}) AND tx by 1 (lx coeff -> {0,1}) = all 8 bank
//   groups distinct -> conflict-free b128; 144 would collide 2-way, r7-measured).
// 27.2 KB LDS -> 5 blocks/CU (launch_bounds(256,5)). Per (dx,dy): 6 taps serve BOTH
// voxels (A slots 0-4, B slots 1-5) = 75 LDS reads/voxel vs r13's 125 (-40% on the
// top pipe: r13 LDS busy ~36us of 50.6us wall).
// XCD swizzle exact: 1728 = 8*216, 216 = one (h,b) -> each XCD owns one 3.5MB k-set.
// fp16 dot2 scores in log2 domain -> bare v_exp_f32; z-validity folded into dot seed
// (0/-16384 -> exp==0 == reference -1000 underflow); xy-mask on aggregates; single
// spatial clamp; cvt_pkrtz staging; dx-grouped accumulation.
// RULE-#20: no local arrays; every per-thread value is a named scalar.

#define S_PLANE 2304      // 48*48
#define S_CHAN 110592     // 48*48*48
#define TOTAL  7077888    // 2*32*S_CHAN

typedef _Float16 h2 __attribute__((ext_vector_type(2)));

__device__ __forceinline__ float dot2(h2 a, h2 b, float c) {
#if __has_builtin(__builtin_amdgcn_fdot2)
    return __builtin_amdgcn_fdot2(a, b, c, false);
#else
    return fmaf((float)a[0], (float)b[0], fmaf((float)a[1], (float)b[1], c));
#endif
}

// bare v_exp_f32 (2^x), no OCML edge-handling (r13: -15%)
__device__ __forceinline__ float fexp2(float x) {
#if __has_builtin(__builtin_amdgcn_exp2f)
    return __builtin_amdgcn_exp2f(x);
#else
    return __exp2f(x);
#endif
}

__device__ __forceinline__ h2 bc(unsigned w) { return __builtin_bit_cast(h2, w); }

// single-instruction pack: v_cvt_pkrtz_f16_f32 (RTZ; k-side only, headroom 3.3x)
__device__ __forceinline__ unsigned pkz(float a, float b) {
#if __has_builtin(__builtin_amdgcn_cvt_pkrtz)
    return __builtin_bit_cast(unsigned, __builtin_amdgcn_cvt_pkrtz(a, b));
#else
    return __builtin_bit_cast(unsigned, h2{(_Float16)a, (_Float16)b});
#endif
}

__global__ __launch_bounds__(256, 5) void mov3d_kernel(
    const float* __restrict__ xq, const float* __restrict__ xk,
    float* __restrict__ out)
{
    __shared__ __align__(16) unsigned kw[6960];   // 1740 lines * 16 B = 27.2 KB

    const int tid = threadIdx.x;
    const int tzi = tid & 3;          // 4 z-pairs (2 voxels each)
    const int ty = (tid >> 2) & 7;    // 8
    const int tx = tid >> 5;          // 8

    // XCD-chunked swizzle: 1728 blocks = 8 XCDs * 216; each chunk = exactly one (h,b)
    const int bid = blockIdx.x;
    int blk = (bid & 7) * 216 + (bid >> 3);

    const int h = blk / 432;
    int rem = blk - h * 432;
    const int b = rem / 216;  rem -= b * 216;
    const int xt = rem / 36;  rem -= xt * 36;
    const int yt = rem / 6;
    const int zt = rem - yt * 6;

    const int x0 = xt * 8, y0 = yt * 8, z0 = zt * 8;
    const int x = x0 + tx, y = y0 + ty, zA = z0 + 2 * tzi;
    const unsigned sp = (unsigned)(x * S_PLANE + y * 48 + zA);
    const int bbase = b * (32 * S_CHAN);

    // hd^-0.5 * log2(e): scores in log2 domain
    const float QSCALE = 0.35355339059327373f * 1.4426950408889634f;

    // ---- q: 8 channels (c = 4k+h), both voxels (z, z+1 -> float2) ----
    const float2 qf0 = *(const float2*)&xq[(unsigned)(bbase + (h     ) * S_CHAN) + sp];
    const float2 qf1 = *(const float2*)&xq[(unsigned)(bbase + (h +  4) * S_CHAN) + sp];
    const float2 qf2 = *(const float2*)&xq[(unsigned)(bbase + (h +  8) * S_CHAN) + sp];
    const float2 qf3 = *(const float2*)&xq[(unsigned)(bbase + (h + 12) * S_CHAN) + sp];
    const float2 qf4 = *(const float2*)&xq[(unsigned)(bbase + (h + 16) * S_CHAN) + sp];
    const float2 qf5 = *(const float2*)&xq[(unsigned)(bbase + (h + 20) * S_CHAN) + sp];
    const float2 qf6 = *(const float2*)&xq[(unsigned)(bbase + (h + 24) * S_CHAN) + sp];
    const float2 qf7 = *(const float2*)&xq[(unsigned)(bbase + (h + 28) * S_CHAN) + sp];
    const h2 qA0 = h2{(_Float16)(qf0.x * QSCALE), (_Float16)(qf1.x * QSCALE)};
    const h2 qA1 = h2{(_Float16)(qf2.x * QSCALE), (_Float16)(qf3.x * QSCALE)};
    const h2 qA2 = h2{(_Float16)(qf4.x * QSCALE), (_Float16)(qf5.x * QSCALE)};
    const h2 qA3 = h2{(_Float16)(qf6.x * QSCALE), (_Float16)(qf7.x * QSCALE)};
    const h2 qB0 = h2{(_Float16)(qf0.y * QSCALE), (_Float16)(qf1.y * QSCALE)};
    const h2 qB1 = h2{(_Float16)(qf2.y * QSCALE), (_Float16)(qf3.y * QSCALE)};
    const h2 qB2 = h2{(_Float16)(qf4.y * QSCALE), (_Float16)(qf5.y * QSCALE)};
    const h2 qB3 = h2{(_Float16)(qf6.y * QSCALE), (_Float16)(qf7.y * QSCALE)};

    // ---- stage K halo: 864 units (z-pair at (lx,ly)); u = lx*72 + lz2*12 + ly ----
    const int sBase = bbase + h * S_CHAN;
#define STAGE_GROUP(G) do {                                                   \
        const int u = (G) * 256 + tid;                                        \
        if ((G) < 3 || tid < 96) {                                            \
            const int lx  = u / 72;                                           \
            const int r   = u - lx * 72;                                      \
            const int lz2 = r / 12;                                           \
            const int ly  = r - lz2 * 12;                                     \
            const int srel0 = (x0 - 2 + lx) * S_PLANE                         \
                            + (y0 - 2 + ly) * 48 + (z0 - 2 + 2 * lz2);        \
            const int srel = min(max(srel0, 0), S_CHAN - 2);                  \
            const int f = sBase + srel;   /* all +c*S_CHAN stay in-bounds */  \
            const float2 vA0 = *(const float2*)&xk[f];                        \
            const float2 vA1 = *(const float2*)&xk[f +  8 * S_CHAN];          \
            const float2 vA2 = *(const float2*)&xk[f + 16 * S_CHAN];          \
            const float2 vA3 = *(const float2*)&xk[f + 24 * S_CHAN];          \
            const float2 vB0 = *(const float2*)&xk[f +  4 * S_CHAN];          \
            const float2 vB1 = *(const float2*)&xk[f + 12 * S_CHAN];          \
            const float2 vB2 = *(const float2*)&xk[f + 20 * S_CHAN];          \
            const float2 vB3 = *(const float2*)&xk[f + 28 * S_CHAN];          \
            const uint4 W0 = {pkz(vA0.x, vB0.x), pkz(vA1.x, vB1.x),           \
                              pkz(vA2.x, vB2.x), pkz(vA3.x, vB3.x)};          \
            const uint4 W1 = {pkz(vA0.y, vB0.y), pkz(vA1.y, vB1.y),           \
                              pkz(vA2.y, vB2.y), pkz(vA3.y, vB3.y)};          \
            const int L0 = lx * 145 + lz2 * 24 + ly;                          \
            *(uint4*)&kw[L0 * 4] = W0;               /* lz even */            \
            *(uint4*)&kw[(L0 + 12) * 4] = W1;        /* lz odd  */            \
        }                                                                     \
    } while (0)
    STAGE_GROUP(0);
    STAGE_GROUP(1);
    STAGE_GROUP(2);
    STAGE_GROUP(3);
#undef STAGE_GROUP
    __syncthreads();   // single barrier

    // z-validity seeds: slot U covers abs z = zA-2+U (A taps U=0..4, B taps U=1..5)
    const float NEG = -16384.f;
    const float zs0 = ((unsigned)(zA - 2) < 48u) ? 0.f : NEG;
    const float zs1 = ((unsigned)(zA - 1) < 48u) ? 0.f : NEG;
    const float zs2 = 0.f;                           // zA in [0,48)
    const float zs3 = ((unsigned)(zA + 1) < 48u) ? 0.f : NEG;
    const float zs4 = ((unsigned)(zA + 2) < 48u) ? 0.f : NEG;
    const float zs5 = ((unsigned)(zA + 3) < 48u) ? 0.f : NEG;

    float lA = 0.f, axA = 0.f, ayA = 0.f, azA = 0.f;
    float lB = 0.f, axB = 0.f, ayB = 0.f, azB = 0.f;

#define SCOREA(T, SEED) \
    dot2(qA0, bc((T).x), dot2(qA1, bc((T).y), dot2(qA2, bc((T).z), dot2(qA3, bc((T).w), (SEED)))))
#define SCOREB(T, SEED) \
    dot2(qB0, bc((T).x), dot2(qB1, bc((T).y), dot2(qB2, bc((T).z), dot2(qB3, bc((T).w), (SEED)))))

    __builtin_amdgcn_s_setprio(1);
#pragma unroll
    for (int dx = -2; dx <= 2; ++dx) {
        const bool vx = (unsigned)(x + dx) < 48u;
        const float fdx = (float)dx;
        float wsdxA = 0.f, wsdxB = 0.f;   // dx-slice subtotals (ax,l folded at dx end)
#pragma unroll
        for (int dy = -2; dy <= 2; ++dy) {
            const bool vxy = vx && ((unsigned)(y + dy) < 48u);
            const float fdy = (float)dy;
            // base line: slot U at line m + U*12 (lz = 2*tzi + U); word offset U*48
            const unsigned* pb = kw
                + ((tx + 2 + dx) * 145 + 2 * tzi * 12 + (ty + 2 + dy)) * 4;

            const uint4 T0 = *(const uint4*)(pb);
            const uint4 T1 = *(const uint4*)(pb + 48);
            const uint4 T2 = *(const uint4*)(pb + 96);
            const uint4 T3 = *(const uint4*)(pb + 144);
            const uint4 T4 = *(const uint4*)(pb + 192);
            const uint4 T5 = *(const uint4*)(pb + 240);

            // voxel A taps slots 0..4, voxel B taps slots 1..5 (shared T1..T4)
            const float eA0 = fexp2(SCOREA(T0, zs0));
            const float eA1 = fexp2(SCOREA(T1, zs1));
            const float eA2 = fexp2(SCOREA(T2, zs2));
            const float eA3 = fexp2(SCOREA(T3, zs3));
            const float eA4 = fexp2(SCOREA(T4, zs4));
            const float eB0 = fexp2(SCOREB(T1, zs1));
            const float eB1 = fexp2(SCOREB(T2, zs2));
            const float eB2 = fexp2(SCOREB(T3, zs3));
            const float eB3 = fexp2(SCOREB(T4, zs4));
            const float eB4 = fexp2(SCOREB(T5, zs5));

            float wsA  = ((eA0 + eA1) + (eA2 + eA3)) + eA4;
            float wsB  = ((eB0 + eB1) + (eB2 + eB3)) + eB4;
            float azPA = fmaf(2.f, eA4 - eA0, eA3 - eA1);
            float azPB = fmaf(2.f, eB4 - eB0, eB3 - eB1);

            // xy-mask applied once on the aggregates (shared by all z-taps)
            wsA  = vxy ? wsA  : 0.f;
            wsB  = vxy ? wsB  : 0.f;
            azPA = vxy ? azPA : 0.f;
            azPB = vxy ? azPB : 0.f;

            wsdxA += wsA;  wsdxB += wsB;
            ayA = fmaf(fdy, wsA, ayA);  ayB = fmaf(fdy, wsB, ayB);
            azA += azPA;  azB += azPB;
        }
        axA = fmaf(fdx, wsdxA, axA);  axB = fmaf(fdx, wsdxB, axB);
        lA += wsdxA;  lB += wsdxB;
    }
    __builtin_amdgcn_s_setprio(0);
#undef SCOREA
#undef SCOREB

    const float rA = 0.25f / lA;
    const float rB = 0.25f / lB;
    const unsigned ob = (unsigned)b * (3 * S_CHAN);
    atomicAdd(&out[ob + 0u * S_CHAN + sp],     axA * rA);
    atomicAdd(&out[ob + 0u * S_CHAN + sp + 1], axB * rB);
    atomicAdd(&out[ob + 1u * S_CHAN + sp],     ayA * rA);
    atomicAdd(&out[ob + 1u * S_CHAN + sp + 1], ayB * rB);
    atomicAdd(&out[ob + 2u * S_CHAN + sp],     azA * rA);
    atomicAdd(&out[ob + 2u * S_CHAN + sp + 1], azB * rB);
}

extern "C" void kernel_launch(void* const* d_in, const int* in_sizes, int n_in,
                              void* d_out, int out_size, void* d_ws, size_t ws_size,
                              hipStream_t stream) {
    const float* xq = (const float*)d_in[0];
    const float* xk = (const float*)d_in[1];
    float* out = (float*)d_out;
    // zero output (heads accumulate via atomicAdd); memset node is graph-capturable
    hipMemsetAsync(out, 0, (size_t)out_size * sizeof(float), stream);
    // grid: 4(head) * 2(b) * 6(xt) * 6(yt) * 6(zt) = 1728 blocks of 256 threads
    mov3d_kernel<<<1728, 256, 0, stream>>>(xq, xk, out);
}

// Round 15
// 50.242 us; speedup vs baseline: 1.3027x; 1.3027x over previous
//
#include <hip/hip_runtime.h>

// MoV3D: 3D local attention, window +-2 (125 offsets), B=2 C=32 H=W=D=48, 4 heads x 8 ch.
// FINAL (= round-13, re-submitted after r14's VZ=2 regression confirmed both failure
// modes: bank-phase layout falsified (166K->4.27M conflicts) and 1728-block occupancy
// quantization (62->40%) -- structural for any VZ=2 tiling at this problem size).
//
// Practical-roofline accounting (r13 counters, 50.6us wall):
//   LDS pipe ~36us busy (71%, top pipe: 125 ds_read_b128/thread, minimal -- each
//   thread reads its 5x5x5 window exactly once, 8 channels per 16B line);
//   VALU ~49% (dot2 floor 22.5us; MFMA rejected: banded Toeplitz <16% util);
//   HBM 8% (XCD-chunked, L2-resident); conflicts 166K (neg.); occupancy 61%.
//
// Structure:
//  - Tile (4x,8y,8z), 1 voxel/thread, 256 threads; halo 8x12x12 = 1152 LDS lines
//    (16B = 8 head channels as fp16 pairs) = 18 KB -> 8 blocks/CU.
//  - XCD-chunked swizzle wg=(bid%8)*432+bid/8 (FETCH 180->28 MB, k-set L2-resident).
//  - Line = lx*144 + lz*12 + ly (ly coeff 1 -> conflict-free b128 under stride-8
//    lane phases; hardware-verified r8/r13).
//  - v_dot2_f32_f16 scores in log2 domain -> bare v_exp_f32 (1 instr; -15% r13);
//    z-validity folded into dot-chain seed (0/-16384 -> exp==0, == reference's
//    -1000 softmax underflow); xy-mask once per (dx,dy) on aggregates;
//    single spatial clamp (all 8 channel addrs provably in-bounds);
//    cvt_pkrtz staging pack; dx-grouped accumulation.
// RULE-#20: no local arrays; every per-thread value is a named scalar.

#define S_PLANE 2304      // 48*48
#define S_CHAN 110592     // 48*48*48
#define TOTAL  7077888    // 2*32*S_CHAN

typedef _Float16 h2 __attribute__((ext_vector_type(2)));

__device__ __forceinline__ float dot2(h2 a, h2 b, float c) {
#if __has_builtin(__builtin_amdgcn_fdot2)
    return __builtin_amdgcn_fdot2(a, b, c, false);
#else
    return fmaf((float)a[0], (float)b[0], fmaf((float)a[1], (float)b[1], c));
#endif
}

// bare v_exp_f32 (2^x), no OCML edge-handling
__device__ __forceinline__ float fexp2(float x) {
#if __has_builtin(__builtin_amdgcn_exp2f)
    return __builtin_amdgcn_exp2f(x);
#else
    return __exp2f(x);
#endif
}

__device__ __forceinline__ h2 bc(unsigned w) { return __builtin_bit_cast(h2, w); }

// single-instruction pack: v_cvt_pkrtz_f16_f32 (RTZ; k-side only, headroom 3.3x)
__device__ __forceinline__ unsigned pkz(float a, float b) {
#if __has_builtin(__builtin_amdgcn_cvt_pkrtz)
    return __builtin_bit_cast(unsigned, __builtin_amdgcn_cvt_pkrtz(a, b));
#else
    return __builtin_bit_cast(unsigned, h2{(_Float16)a, (_Float16)b});
#endif
}

__global__ __launch_bounds__(256, 8) void mov3d_kernel(
    const float* __restrict__ xq, const float* __restrict__ xk,
    float* __restrict__ out)
{
    __shared__ __align__(16) unsigned kw[4608];   // 1152 lines * 16 B = 18 KB

    const int tid = threadIdx.x;
    const int tz8 = tid & 7;          // z within tile
    const int ty = (tid >> 3) & 7;    // y within tile
    const int tx = tid >> 6;          // x within tile (wave index)

    // XCD-chunked swizzle: 3456 blocks, 8 XCDs, 432 per chunk (bijective).
    const int bid = blockIdx.x;
    int blk = (bid & 7) * 432 + (bid >> 3);

    const int h = blk / 864;
    int rem = blk - h * 864;
    const int zt = rem % 6;  rem /= 6;
    const int yt = rem % 6;  rem /= 6;
    const int xt = rem % 12;
    const int b  = rem / 12;

    const int x0 = xt * 4, y0 = yt * 8, z0 = zt * 8;
    const int x = x0 + tx, y = y0 + ty, z = z0 + tz8;
    const unsigned sp = (unsigned)(x * S_PLANE + y * 48 + z);
    const int bbase = b * (32 * S_CHAN);

    // hd^-0.5 * log2(e): scores in log2 domain
    const float QSCALE = 0.35355339059327373f * 1.4426950408889634f;

    // ---- q: 8 channels (c = 4k+h) at this voxel; pack into 4 fp16 pairs (RNE) ----
    const float qf0 = xq[(unsigned)(bbase + (h     ) * S_CHAN) + sp];
    const float qf1 = xq[(unsigned)(bbase + (h +  4) * S_CHAN) + sp];
    const float qf2 = xq[(unsigned)(bbase + (h +  8) * S_CHAN) + sp];
    const float qf3 = xq[(unsigned)(bbase + (h + 12) * S_CHAN) + sp];
    const float qf4 = xq[(unsigned)(bbase + (h + 16) * S_CHAN) + sp];
    const float qf5 = xq[(unsigned)(bbase + (h + 20) * S_CHAN) + sp];
    const float qf6 = xq[(unsigned)(bbase + (h + 24) * S_CHAN) + sp];
    const float qf7 = xq[(unsigned)(bbase + (h + 28) * S_CHAN) + sp];
    const h2 qA0 = h2{(_Float16)(qf0 * QSCALE), (_Float16)(qf1 * QSCALE)};
    const h2 qA1 = h2{(_Float16)(qf2 * QSCALE), (_Float16)(qf3 * QSCALE)};
    const h2 qA2 = h2{(_Float16)(qf4 * QSCALE), (_Float16)(qf5 * QSCALE)};
    const h2 qA3 = h2{(_Float16)(qf6 * QSCALE), (_Float16)(qf7 * QSCALE)};

    // ---- stage K halo: thread u covers z-pair (2*lz2, 2*lz2+1) at (lx,ly) ----
    const int sBase = bbase + h * S_CHAN;
#define STAGE_GROUP(G) do {                                                   \
        const int u = (G) * 256 + tid;                                        \
        if ((G) < 2 || tid < 64) {                                            \
            const int lx  = u / 72;                                           \
            const int r   = u - lx * 72;                                      \
            const int lz2 = r / 12;                                           \
            const int ly  = r - lz2 * 12;                                     \
            const int srel0 = (x0 - 2 + lx) * S_PLANE                         \
                            + (y0 - 2 + ly) * 48 + (z0 - 2 + 2 * lz2);        \
            const int srel = min(max(srel0, 0), S_CHAN - 2);                  \
            const int f = sBase + srel;   /* all +c*S_CHAN stay in-bounds */  \
            const float2 vA0 = *(const float2*)&xk[f];                        \
            const float2 vA1 = *(const float2*)&xk[f +  8 * S_CHAN];          \
            const float2 vA2 = *(const float2*)&xk[f + 16 * S_CHAN];          \
            const float2 vA3 = *(const float2*)&xk[f + 24 * S_CHAN];          \
            const float2 vB0 = *(const float2*)&xk[f +  4 * S_CHAN];          \
            const float2 vB1 = *(const float2*)&xk[f + 12 * S_CHAN];          \
            const float2 vB2 = *(const float2*)&xk[f + 20 * S_CHAN];          \
            const float2 vB3 = *(const float2*)&xk[f + 28 * S_CHAN];          \
            const uint4 W0 = {pkz(vA0.x, vB0.x), pkz(vA1.x, vB1.x),           \
                              pkz(vA2.x, vB2.x), pkz(vA3.x, vB3.x)};          \
            const uint4 W1 = {pkz(vA0.y, vB0.y), pkz(vA1.y, vB1.y),           \
                              pkz(vA2.y, vB2.y), pkz(vA3.y, vB3.y)};          \
            const int L0 = lx * 144 + lz2 * 24 + ly;                          \
            *(uint4*)&kw[L0 * 4] = W0;                                        \
            *(uint4*)&kw[(L0 + 12) * 4] = W1;                                 \
        }                                                                     \
    } while (0)
    STAGE_GROUP(0);
    STAGE_GROUP(1);
    STAGE_GROUP(2);
#undef STAGE_GROUP
    __syncthreads();   // single barrier

    // z-validity seeds: slot U covers abs z-2+U; invalid -> exp2(dot-16384) == 0
    const float NEG = -16384.f;
    const float zs0 = ((unsigned)(z - 2) < 48u) ? 0.f : NEG;
    const float zs1 = ((unsigned)(z - 1) < 48u) ? 0.f : NEG;
    const float zs2 = 0.f;                           // z in [0,48)
    const float zs3 = ((unsigned)(z + 1) < 48u) ? 0.f : NEG;
    const float zs4 = ((unsigned)(z + 2) < 48u) ? 0.f : NEG;

    float l = 0.f, ax = 0.f, ay = 0.f, az = 0.f;

#define SCORE(T, SEED) \
    dot2(qA0, bc((T).x), dot2(qA1, bc((T).y), dot2(qA2, bc((T).z), dot2(qA3, bc((T).w), (SEED)))))

    __builtin_amdgcn_s_setprio(1);
#pragma unroll
    for (int dx = -2; dx <= 2; ++dx) {
        const bool vx = (unsigned)(x + dx) < 48u;
        const float fdx = (float)dx;
        float wsdx = 0.f;                 // dx-slice weight subtotal (ax,l folded at end)
#pragma unroll
        for (int dy = -2; dy <= 2; ++dy) {
            const bool vxy = vx && ((unsigned)(y + dy) < 48u);
            const float fdy = (float)dy;
            // base line: taps at line m + U*12, U = 0..4 (lz = tz8 + U)
            const unsigned* pb = kw
                + ((tx + 2 + dx) * 144 + tz8 * 12 + (ty + 2 + dy)) * 4;

            const uint4 T0 = *(const uint4*)(pb);
            const uint4 T1 = *(const uint4*)(pb + 48);
            const uint4 T2 = *(const uint4*)(pb + 96);
            const uint4 T3 = *(const uint4*)(pb + 144);
            const uint4 T4 = *(const uint4*)(pb + 192);

            const float e0 = fexp2(SCORE(T0, zs0));
            const float e1 = fexp2(SCORE(T1, zs1));
            const float e2 = fexp2(SCORE(T2, zs2));
            const float e3 = fexp2(SCORE(T3, zs3));
            const float e4 = fexp2(SCORE(T4, zs4));

            float ws  = ((e0 + e1) + (e2 + e3)) + e4;
            float azP = fmaf(2.f, e4 - e0, e3 - e1);

            // xy-mask applied once on the aggregates (shared by all 5 z-taps)
            ws  = vxy ? ws  : 0.f;
            azP = vxy ? azP : 0.f;

            wsdx += ws;
            ay = fmaf(fdy, ws, ay);
            az += azP;
        }
        ax = fmaf(fdx, wsdx, ax);
        l += wsdx;
    }
    __builtin_amdgcn_s_setprio(0);
#undef SCORE

    const float r = 0.25f / l;
    const unsigned ob = (unsigned)b * (3 * S_CHAN);
    atomicAdd(&out[ob + 0u * S_CHAN + sp], ax * r);
    atomicAdd(&out[ob + 1u * S_CHAN + sp], ay * r);
    atomicAdd(&out[ob + 2u * S_CHAN + sp], az * r);
}

extern "C" void kernel_launch(void* const* d_in, const int* in_sizes, int n_in,
                              void* d_out, int out_size, void* d_ws, size_t ws_size,
                              hipStream_t stream) {
    const float* xq = (const float*)d_in[0];
    const float* xk = (const float*)d_in[1];
    float* out = (float*)d_out;
    // zero output (heads accumulate via atomicAdd); memset node is graph-capturable
    hipMemsetAsync(out, 0, (size_t)out_size * sizeof(float), stream);
    // grid: 4(head) * 2(b) * 12(xt) * 6(yt) * 6(zt) = 3456 blocks of 256 threads
    mov3d_kernel<<<3456, 256, 0, stream>>>(xq, xk, out);
}